// Round 2
// baseline (1133.834 us; speedup 1.0000x reference)
//
#include <hip/hip_runtime.h>

#define NU 10000
#define NREV_DST 8000
#define MAIN_BLOCKS 2500   // 2500 blocks x 4 waves = 10000 users, one user per wave

// ws float layout:
//   [0)        Bstate[8*128]   = 1024
//   [1024)     delta_acc[512]
//   [1536)     Wbuf[64*8]      = 512   (TRANSPOSED: W[n][k] at n*8+k)
//   [2048)     allu[NU*16*64]  = 10,240,000
//   [10242048) embS[40000*64]  = 2,560,000  (shared scratch: E@S for the table
//              used by the CURRENT call; recomputed between calls => 51.2 MB total)

// out[r][d] = sum_e E[r][e] * S[e][d]   (exactly the reference's low_new transform)
// S columns live in VGPRs (lane = d); row values are wave-uniform -> s_load batches.
__global__ __launch_bounds__(256) void embS_kernel(
    const float* __restrict__ E, const float* __restrict__ Sg,
    float* __restrict__ out, int nrows)
{
    const int tid = threadIdx.x, w = tid >> 6, lane = tid & 63;
    float Sc[64];
#pragma unroll
    for (int e = 0; e < 64; ++e) Sc[e] = Sg[e * 64 + lane];  // coalesced column load
    const int nw = gridDim.x * 4;
    for (int r0 = blockIdx.x * 4 + w; r0 < nrows; r0 += nw) {
        const int r = __builtin_amdgcn_readfirstlane(r0);
        const float* row = E + (size_t)r * 64;
        float acc = 0.f;
#pragma unroll
        for (int e = 0; e < 64; ++e)
            acc = fmaf(row[e], Sc[e], acc);  // row[e] uniform -> s_load; single chain = einsum order
        out[(size_t)r * 64 + lane] = acc;
    }
}

template <int N, int K>
__global__ __launch_bounds__(256, 6) void main_iter(
    const float* __restrict__ embS, const int* __restrict__ idx,
    const float* __restrict__ Wg,
    float* __restrict__ delta_acc, float* __restrict__ allu,
    int slot0, int write_high, int write_delta)
{
    // per-wave slab: 64 rows x 16-wide e-slice (time-multiplexed), stride 20 floats
    __shared__ float s_slab[4][64 * 20];
    __shared__ float s_h[4][K * 64];   // hi[k][d], broadcast-read in phase D

    const int tid  = threadIdx.x;
    const int w    = tid >> 6;
    const int lane = tid & 63;

    const int u = __builtin_amdgcn_readfirstlane((int)blockIdx.x * 4 + w);
    const int* uidx = idx + u * N;

    // ---- phase A: raw[k][d=lane] = sum_n W[n][k] * embS[idx[n]][lane]
    // rows wave-uniform -> coalesced 256B broadcast-row loads; W via s_load. No LDS, no readlane.
    float raw[K];
#pragma unroll
    for (int k = 0; k < K; ++k) raw[k] = 0.f;
#pragma unroll
    for (int r0 = 0; r0 < N; r0 += 8) {
        float ev[8];
#pragma unroll
        for (int i = 0; i < 8; ++i)
            if (r0 + i < N) {
                const int row = uidx[r0 + i];          // s_load (uniform)
                ev[i] = embS[(size_t)row * 64 + lane]; // coalesced row
            }
#pragma unroll
        for (int i = 0; i < 8; ++i)
            if (r0 + i < N) {
#pragma unroll
                for (int k = 0; k < K; ++k)
                    raw[k] = fmaf(Wg[(r0 + i) * 8 + k], ev[i], raw[k]);  // W via s_load
            }
    }

    // ---- squash (same expression/order as before)
    float sq = 0.f;
#pragma unroll
    for (int k = 0; k < K; ++k) sq = fmaf(raw[k], raw[k], sq);
    const float f = (sq / (1.0f + sq)) / sqrtf(sq + 1e-9f);
    float hi[K];
#pragma unroll
    for (int k = 0; k < K; ++k) hi[k] = f * raw[k];

    if (write_high) {
#pragma unroll
        for (int k = 0; k < K; ++k)
            allu[(size_t)u * 1024 + (slot0 + k) * 64 + lane] = hi[k];
    }

    if (write_delta) {
        // ---- phase D: delta[k][n=lane] = sum_d embS[idx[n]][d] * hi[k][d]
        // e-chunked staging of the same (cache-hot) rows; hi broadcast via
        // same-address ds_read_b128 (conflict-free broadcast, off the VALU pipe).
#pragma unroll
        for (int k = 0; k < K; ++k) s_h[w][k * 64 + lane] = hi[k];

        float dreg[K];
#pragma unroll
        for (int k = 0; k < K; ++k) dreg[k] = 0.f;

        constexpr int RP = (N + 15) / 16;
        const int rr = lane >> 2, jj = lane & 3;
        int rows[RP];
#pragma unroll
        for (int p = 0; p < RP; ++p) {
            const int r = p * 16 + rr;
            rows[p] = (N % 16 == 0 || r < N) ? uidx[r] : 0;
        }

        for (int ec = 0; ec < 4; ++ec) {
            const int e0 = ec * 16;
#pragma unroll
            for (int p = 0; p < RP; ++p) {
                const int r = p * 16 + rr;
                if (N % 16 == 0 || r < N) {
                    const float4 v =
                        *(const float4*)(embS + (size_t)rows[p] * 64 + e0 + jj * 4);
                    *(float4*)&s_slab[w][r * 20 + jj * 4] = v;  // wave-private slab
                }
            }
#pragma unroll
            for (int e4 = 0; e4 < 4; ++e4) {
                const float4 v = *(const float4*)&s_slab[w][lane * 20 + e4 * 4];
#pragma unroll
                for (int k = 0; k < K; ++k) {
                    const float4 h = *(const float4*)&s_h[w][k * 64 + e0 + e4 * 4];
                    dreg[k] = fmaf(v.x, h.x, dreg[k]);
                    dreg[k] = fmaf(v.y, h.y, dreg[k]);
                    dreg[k] = fmaf(v.z, h.z, dreg[k]);
                    dreg[k] = fmaf(v.w, h.w, dreg[k]);
                }
            }
        }

        // cross-wave reduce (reuse slabs), one atomic per (k,n) per block
#pragma unroll
        for (int k = 0; k < K; ++k) s_slab[w][k * 64 + lane] = dreg[k];
        __syncthreads();
        for (int t = tid; t < K * 64; t += 256) {
            const float s = s_slab[0][t] + s_slab[1][t] + s_slab[2][t] + s_slab[3][t];
            if ((t & 63) < N) atomicAdd(&delta_acc[t], s);  // lanes>=N hold garbage -> masked
        }
    }
}

// Apply delta -> B, zero delta, compute next softmax W (transposed layout n*8+k).
__global__ __launch_bounds__(1024) void update_kernel(
    float* __restrict__ Bstate, float* __restrict__ delta_acc,
    const float* __restrict__ Bin, float* __restrict__ Wout,
    int init, int Kc, int nc, int Kn, int nn)
{
    __shared__ float sB[1024];
    const int t = threadIdx.x;
    float b = init ? Bin[t] : Bstate[t];
    const int k = t >> 7, n = t & 127;
    float d = 0.f;
    if (!init && k < Kc && n < nc) d = delta_acc[k * 64 + n];
    __syncthreads();
    if (t < 512) delta_acc[t] = 0.f;  // fresh accumulator for next main launch
    b += d;
    Bstate[t] = b;
    sB[t] = b;
    __syncthreads();
    const int wv = t >> 6, lane = t & 63;
    if (wv < Kn) {
        float v = (lane < nn) ? sB[wv * 128 + lane] : -3.4e38f;
        float m = v;
#pragma unroll
        for (int off = 32; off >= 1; off >>= 1) m = fmaxf(m, __shfl_xor(m, off, 64));
        const float e = (lane < nn) ? expf(v - m) : 0.f;
        float s = e;
#pragma unroll
        for (int off = 32; off >= 1; off >>= 1) s += __shfl_xor(s, off, 64);
        Wout[lane * 8 + wv] = e / s;  // transposed: W[n][k]
    }
}

__global__ __launch_bounds__(256) void attn_kernel(
    const float* __restrict__ allu, const float* __restrict__ M1g,
    const float* __restrict__ M2g, float* __restrict__ out)
{
    __shared__ float sM1[64 * 65];
    __shared__ float sU[4][16 * 64];
    const int tid = threadIdx.x, w = tid >> 6, lane = tid & 63;
    for (int i = tid; i < 4096; i += 256)
        sM1[(i >> 6) * 65 + (i & 63)] = M1g[i];
    __syncthreads();
    const int u = blockIdx.x * 4 + w;
    if (u >= NU) return;
    for (int i = 0; i < 16; ++i)
        sU[w][i * 64 + lane] = allu[(size_t)u * 1024 + i * 64 + lane];
    const float m2 = M2g[lane];
    float acc[16];
#pragma unroll
    for (int i = 0; i < 16; ++i) acc[i] = 0.f;
    for (int d = 0; d < 64; ++d) {
        const float m1v = sM1[d * 65 + lane];
#pragma unroll
        for (int i = 0; i < 16; ++i) acc[i] = fmaf(sU[w][i * 64 + d], m1v, acc[i]);
    }
    float s2[16];
#pragma unroll
    for (int i = 0; i < 16; ++i) {
        float c = tanhf(acc[i]) * m2;
#pragma unroll
        for (int off = 32; off >= 1; off >>= 1) c += __shfl_xor(c, off, 64);
        s2[i] = c * c;
    }
    float mx = 0.f;  // 8 padded slots have s=0
#pragma unroll
    for (int i = 0; i < 16; ++i) mx = fmaxf(mx, s2[i]);
    float den = 8.f * expf(-mx);
    float att[16];
#pragma unroll
    for (int i = 0; i < 16; ++i) { att[i] = expf(s2[i] - mx); den += att[i]; }
    const float inv = 1.0f / den;
    float o = 0.f;
#pragma unroll
    for (int i = 0; i < 16; ++i) o = fmaf(att[i] * inv, sU[w][i * 64 + lane], o);
    out[(size_t)u * 64 + lane] = o;
}

__global__ __launch_bounds__(256) void review_kernel(
    const float* __restrict__ tag, const int* __restrict__ idx, float* __restrict__ out)
{
    const int tid = threadIdx.x, w = tid >> 6, lane = tid & 63;
    const int r = blockIdx.x * 4 + w;
    if (r >= NREV_DST) return;
    float acc = 0.f;
    for (int j = 0; j < 20; ++j) {
        const int t = idx[r * 20 + j];
        acc += tag[(size_t)t * 64 + lane];
    }
    out[(size_t)r * 64 + lane] = acc / 20.0f;
}

extern "C" void kernel_launch(void* const* d_in, const int* in_sizes, int n_in,
                              void* d_out, int out_size, void* d_ws, size_t ws_size,
                              hipStream_t stream)
{
    const float* review_embed = (const float*)d_in[0];
    const float* tag_embed    = (const float*)d_in[1];
    const int*   idx_urt      = (const int*)d_in[2];
    const int*   idx_uqt      = (const int*)d_in[3];
    const int*   idx_uprt     = (const int*)d_in[4];
    const int*   idx_rht      = (const int*)d_in[5];
    const float* B_in         = (const float*)d_in[6];
    const float* S_g          = (const float*)d_in[7];
    const float* M1           = (const float*)d_in[8];
    const float* M2           = (const float*)d_in[9];

    float* ws     = (float*)d_ws;
    float* Bstate = ws;
    float* delta  = ws + 1024;
    float* Wbuf   = ws + 1536;
    float* allu   = ws + 2048;
    float* embS   = ws + 2048 + (size_t)NU * 1024;  // 2,560,000 floats scratch
    float* out    = (float*)d_out;

    const dim3 mg(MAIN_BLOCKS), mb(256);
    const dim3 one(1), ub(1024), pg(512);

    // embS = review_embed @ S  (calls 1 uses review table)
    hipLaunchKernelGGL(embS_kernel, pg, mb, 0, stream, review_embed, S_g, embS, 30000);
    // init: copy B, zero delta, W for call1 (K=6, n=64)
    hipLaunchKernelGGL(update_kernel, one, ub, 0, stream,
                       Bstate, delta, B_in, Wbuf, 1, 0, 0, 6, 64);

    // call 1: review_embed[idx_urt], n=64, K=6, slots 0..5
    for (int itr = 0; itr < 3; ++itr) {
        hipLaunchKernelGGL((main_iter<64, 6>), mg, mb, 0, stream,
                           embS, idx_urt, Wbuf, delta, allu,
                           0, (itr == 2) ? 1 : 0, 1);
        const int Kn = (itr == 2) ? 5 : 6;
        const int nn = (itr == 2) ? 32 : 64;
        hipLaunchKernelGGL(update_kernel, one, ub, 0, stream,
                           Bstate, delta, B_in, Wbuf, 0, 6, 64, Kn, nn);
    }

    // embS = tag_embed @ S  (call 2 uses tag table)
    hipLaunchKernelGGL(embS_kernel, pg, mb, 0, stream, tag_embed, S_g, embS, 40000);
    // call 2: tag_embed[idx_uqt], n=32, K=5, slots 6..10
    for (int itr = 0; itr < 3; ++itr) {
        hipLaunchKernelGGL((main_iter<32, 5>), mg, mb, 0, stream,
                           embS, idx_uqt, Wbuf, delta, allu,
                           6, (itr == 2) ? 1 : 0, 1);
        const int nn = (itr == 2) ? 50 : 32;
        hipLaunchKernelGGL(update_kernel, one, ub, 0, stream,
                           Bstate, delta, B_in, Wbuf, 0, 5, 32, 5, nn);
    }

    // embS = review_embed @ S again (call 3 uses review table)
    hipLaunchKernelGGL(embS_kernel, pg, mb, 0, stream, review_embed, S_g, embS, 30000);
    // call 3: review_embed[idx_uprt], n=50, K=5, slots 11..15
    for (int itr = 0; itr < 3; ++itr) {
        const int last = (itr == 2);
        hipLaunchKernelGGL((main_iter<50, 5>), mg, mb, 0, stream,
                           embS, idx_uprt, Wbuf, delta, allu,
                           11, last, last ? 0 : 1);
        if (!last)
            hipLaunchKernelGGL(update_kernel, one, ub, 0, stream,
                               Bstate, delta, B_in, Wbuf, 0, 5, 50, 5, 50);
    }

    hipLaunchKernelGGL(attn_kernel, dim3((NU + 3) / 4), mb, 0, stream, allu, M1, M2, out);
    hipLaunchKernelGGL(review_kernel, dim3((NREV_DST + 3) / 4), mb, 0, stream,
                       tag_embed, idx_rht, out + (size_t)NU * 64);
}